// Round 1
// 65.009 us; speedup vs baseline: 1.0418x; 1.0418x over previous
//
#include <hip/hip_runtime.h>
#include <math.h>

// GraphPoolMol: B=64, MAX_ATOM=128, N_FEAT=128
// out[b,i,f] = i<n ? max_{j<n, L[b,i,j]!=0} x[b,j,f] (fallback x[b,i,f] if no nbr) : 0
//
// Structure: one WAVE per output row (i). No barriers, no atomics.
//  - neighbor compaction: ballot + mbcnt prefix-popcount (wave-local)
//  - float2 per lane: 64 lanes x 8B = full 512B row per load instruction
//  - neighbor loop unrolled x4: 4 independent L2-hit loads in flight

#define MAX_ATOM 128
#define N_FEAT 128
#define B_SIZE 64
#define WAVES_PER_BLOCK 4

__global__ __launch_bounds__(64 * WAVES_PER_BLOCK) void GraphPoolMol_kernel(
    const float* __restrict__ x,       // (B, MAX_ATOM, N_FEAT)
    const float* __restrict__ L,       // (B, MAX_ATOM, MAX_ATOM)
    const int* __restrict__ mol_slice, // (B, 2) -- col 0 = n_atoms
    float* __restrict__ out)           // (B, MAX_ATOM, N_FEAT)
{
    const int lane = threadIdx.x & 63;
    const int w    = threadIdx.x >> 6;              // wave id within block
    const int i    = blockIdx.x * WAVES_PER_BLOCK + w;  // atom row
    const int b    = blockIdx.y;                    // batch

    const int n = mol_slice[b * 2];                 // uniform -> s_load

    float2* __restrict__ orow =
        (float2*)(out + ((size_t)b * MAX_ATOM + i) * N_FEAT);

    if (i >= n) {                                   // padded row: zeros
        orow[lane] = make_float2(0.0f, 0.0f);
        return;                                     // safe: no barriers anywhere
    }

    const float* __restrict__ xb = x + (size_t)b * MAX_ATOM * N_FEAT;
    const float2* __restrict__ Lrow =
        (const float2*)(L + ((size_t)b * MAX_ATOM + i) * MAX_ATOM);

    __shared__ int nbr[WAVES_PER_BLOCK][MAX_ATOM];  // 2 KB total

    // ---- wave-local neighbor-list compaction (no atomics, no barriers) ----
    const float2 lv = Lrow[lane];                   // columns 2*lane, 2*lane+1
    const int  j0 = 2 * lane, j1 = 2 * lane + 1;
    const bool p0 = (j0 < n) && (lv.x != 0.0f);
    const bool p1 = (j1 < n) && (lv.y != 0.0f);
    const unsigned long long m0 = __ballot(p0);
    const unsigned long long m1 = __ballot(p1);
    // popcount of mask bits strictly below this lane (mbcnt idiom)
    const int below0 = __builtin_amdgcn_mbcnt_hi((unsigned)(m0 >> 32),
                        __builtin_amdgcn_mbcnt_lo((unsigned)m0, 0u));
    const int below1 = __builtin_amdgcn_mbcnt_hi((unsigned)(m1 >> 32),
                        __builtin_amdgcn_mbcnt_lo((unsigned)m1, 0u));
    const int c0 = __popcll(m0);
    const int m  = c0 + __popcll(m1);               // neighbor count (>=1: diag==1)
    if (p0) nbr[w][below0]      = j0;
    if (p1) nbr[w][c0 + below1] = j1;
    // Same-wave LDS RAW: DS pipe is in-order per wave; fence pins compiler order
    // and drains the writes before the broadcast reads below.
    asm volatile("s_waitcnt lgkmcnt(0)" ::: "memory");

    // ---- max over neighbor rows; 4 loads in flight per step ----
    float ax = -INFINITY, ay = -INFINITY;
    int k = 0;
    for (; k + 4 <= m; k += 4) {
        const int ja = nbr[w][k + 0];               // ds_read_b128 broadcast
        const int jb = nbr[w][k + 1];
        const int jc = nbr[w][k + 2];
        const int jd = nbr[w][k + 3];
        const float2 va = ((const float2*)(xb + (size_t)ja * N_FEAT))[lane];
        const float2 vb = ((const float2*)(xb + (size_t)jb * N_FEAT))[lane];
        const float2 vc = ((const float2*)(xb + (size_t)jc * N_FEAT))[lane];
        const float2 vd = ((const float2*)(xb + (size_t)jd * N_FEAT))[lane];
        ax = fmaxf(ax, fmaxf(fmaxf(va.x, vb.x), fmaxf(vc.x, vd.x)));
        ay = fmaxf(ay, fmaxf(fmaxf(va.y, vb.y), fmaxf(vc.y, vd.y)));
    }
    for (; k < m; ++k) {
        const int j = nbr[w][k];
        const float2 v = ((const float2*)(xb + (size_t)j * N_FEAT))[lane];
        ax = fmaxf(ax, v.x);
        ay = fmaxf(ay, v.y);
    }
    if (m == 0) {   // unreachable (L diagonal is exactly 1.0), kept for fidelity
        const float2 v = ((const float2*)(xb + (size_t)i * N_FEAT))[lane];
        ax = v.x; ay = v.y;
    }
    orow[lane] = make_float2(ax, ay);               // coalesced 512B row store
}

extern "C" void kernel_launch(void* const* d_in, const int* in_sizes, int n_in,
                              void* d_out, int out_size, void* d_ws, size_t ws_size,
                              hipStream_t stream) {
    const float* x   = (const float*)d_in[0];   // node_features (64,128,128) f32
    const float* L   = (const float*)d_in[1];   // laplacian     (64,128,128) f32
    const int* mol   = (const int*)d_in[2];     // mol_slice     (64,2) i32
    // d_in[3] = l_slice (unused)
    float* out = (float*)d_out;

    dim3 grid(MAX_ATOM / WAVES_PER_BLOCK, B_SIZE);  // (32, 64) = 2048 blocks
    dim3 block(64 * WAVES_PER_BLOCK);               // 256 threads = 4 waves
    GraphPoolMol_kernel<<<grid, block, 0, stream>>>(x, L, mol, out);
}